// Round 10
// baseline (302.006 us; speedup 1.0000x reference)
//
#include <hip/hip_runtime.h>
#include <math.h>

// Conv-KNRM on MI355X. B=128, QLEN=30, DLEN=256, EMB=300, C=128.
//
// R10: 3 dispatches. R8/R9 post-mortem: per-producer __threadfence() (device
// fence => per-XCD L2 writeback+invalidate, ~3072 serialized) cost ~180us and
// thrashed co-resident blocks' L2 (FETCH 14->30MB). Fix: producers write pkq8
// partials with RELAXED AGENT-scope stores (global_store sc1 -> coherence
// point, no L2 writeback), release via s_waitcnt vmcnt(0) + RELAXED agent
// fetch_add(cnt[b]) (no compiler-inserted wbl2); 24th arrival reads partials
// with RELAXED AGENT loads (sc1, bypasses stale L2). Zero full fences.
//
//   prep_w      : weights -> wt2 bf16 frag-order; block0 zeroes cnt[128].
//   conv_all    : 1152 blocks x 512 thr; NI=2; fp32->bf16 fused staging;
//                 A=w frags global (compiler wfA/wfB prefetch), B=x LDS;
//                 bias+relu+L2norm -> bf16 [g][b][l][c]. (R4: VGPR 40)
//   pool_finish : 3072 single-wave blocks (tg,chunk,b). MFMA cos + RBF x11,
//                 quad shfl d-sum; sc1 stores into pkq8[chunk][pair][b][q][kk];
//                 vmcnt(0) + relaxed agent inc(cnt[b]); 24th block sums the
//                 8 chunks (sc1 loads), log/qmask/dense-dot -> out[b].
//
// ws (shorts): wt2@0 (245760) | pkq8(f32 3041280)@245760 | cnt@6328320
//              | qn@12042240 (1474560) | dn@13516800 (12582912)

typedef __bf16 bf16x8 __attribute__((ext_vector_type(8)));
typedef float f32x4 __attribute__((ext_vector_type(4)));

#if __has_builtin(__builtin_amdgcn_exp2f)
#define EXP2F(x) __builtin_amdgcn_exp2f(x)
#else
#define EXP2F(x) exp2f(x)
#endif

#define AS_STRIDE 344  // shorts; 688 B row: 2-way b128 (free), 16B-aligned

static __device__ __forceinline__ unsigned short f2bf(float f) {
  union { float f; unsigned int u; } v; v.f = f;
  unsigned int r = v.u + 0x7FFFu + ((v.u >> 16) & 1u);  // RNE
  return (unsigned short)(r >> 16);
}

// weights -> frag order (exactly 960*256 = 245760 elems); block0 re-arms cnt
__global__ __launch_bounds__(256) void prep_w(
    const float* __restrict__ w1, const float* __restrict__ w2,
    const float* __restrict__ w3, unsigned short* __restrict__ wt2,
    unsigned int* __restrict__ cnt) {
  if (blockIdx.x == 0 && threadIdx.x < 128) cnt[threadIdx.x] = 0u;
  int idx = blockIdx.x * 256 + threadIdx.x;
  if (idx >= 245760) return;
  int jj   = idx & 7;
  int lane = (idx >> 3) & 63;
  int ec   = (idx >> 9) % 10;
  int cb   = (idx / 5120) & 7;
  int p    = idx / 40960;
  const float* w; int k, jt;
  if (p == 0)      { w = w1; k = 1; jt = 0; }
  else if (p <= 2) { w = w2; k = 2; jt = p - 1; }
  else             { w = w3; k = 3; jt = p - 3; }
  int c = cb * 16 + (lane & 15);
  int e = ec * 32 + (lane >> 4) * 8 + jj;
  float v = (e < 300) ? w[(c * 300 + e) * k + jt] : 0.0f;
  wt2[idx] = f2bf(v);
}

// Wave tile: NI*16 l-rows x 48 ch (cb=w: 16 ch in each of 3 grams).
// A-operand = weights (frag-order global, reg-dbuf prefetch), B = x (LDS,
// fp32->bf16 packed during staging). R4-proven (VGPR 40, no spills).
// plane p -> (j,g): {0,0},{0,1},{1,1},{0,2},{1,2},{2,2}
template<int NI>
__device__ __forceinline__ void conv_body(
    unsigned short* As, float* psq,  // psq[8][3][NI*16]
    const float* __restrict__ xs, int L, int l0, int b,
    const unsigned short* __restrict__ wt2,
    const float* __restrict__ b1, const float* __restrict__ b2,
    const float* __restrict__ b3,
    unsigned short* __restrict__ out) {
  constexpr int ROWS = NI * 16 + 2;
  constexpr int NR = NI * 16;
  const int t = threadIdx.x;
  const int w = __builtin_amdgcn_readfirstlane(t >> 6);  // cb 0..7
  const int lane = t & 63;
  const int quad = lane >> 4, lrow = lane & 15;

  // stage A: fp32 -> bf16 pack, ROWS x 40 uint4 (tail e>=296 zero-guarded)
  for (int idx = t; idx < ROWS * 40; idx += 512) {
    int r = idx / 40, c = idx % 40;
    int l = l0 + r;
    int e = c * 8;
    float4 a = make_float4(0.f, 0.f, 0.f, 0.f);
    float4 cc = make_float4(0.f, 0.f, 0.f, 0.f);
    if (l < L) {
      const float* src = xs + (size_t)l * 300;
      if (e < 300)     a  = *reinterpret_cast<const float4*>(src + e);
      if (e + 4 < 300) cc = *reinterpret_cast<const float4*>(src + e + 4);
    }
    uint4 o;
    o.x = (unsigned int)f2bf(a.x) | ((unsigned int)f2bf(a.y) << 16);
    o.y = (unsigned int)f2bf(a.z) | ((unsigned int)f2bf(a.w) << 16);
    o.z = (unsigned int)f2bf(cc.x) | ((unsigned int)f2bf(cc.y) << 16);
    o.w = (unsigned int)f2bf(cc.z) | ((unsigned int)f2bf(cc.w) << 16);
    *reinterpret_cast<uint4*>(&As[r * AS_STRIDE + c * 8]) = o;
  }

  f32x4 acc[NI][3];
  #pragma unroll
  for (int ni = 0; ni < NI; ++ni)
    #pragma unroll
    for (int g = 0; g < 3; ++g) acc[ni][g] = (f32x4){0.f, 0.f, 0.f, 0.f};

  const unsigned short* wl = wt2 + (size_t)lane * 8;

  auto wfld = [&](bf16x8* dst, int ec) {
    #pragma unroll
    for (int p = 0; p < 6; ++p)
      dst[p] = *reinterpret_cast<const bf16x8*>(
          wl + ((((p * 8 + w) * 10 + ec) << 9)));
  };

  auto compute = [&](const bf16x8* wf, int ec) {
    bf16x8 xf[3][NI];
    #pragma unroll
    for (int j = 0; j < 3; ++j)
      #pragma unroll
      for (int ni = 0; ni < NI; ++ni)
        xf[j][ni] = *reinterpret_cast<const bf16x8*>(
            &As[(ni * 16 + lrow + j) * AS_STRIDE + ec * 32 + quad * 8]);
    const int PJ[6] = {0, 0, 1, 0, 1, 2};
    const int PG[6] = {0, 1, 1, 2, 2, 2};
    #pragma unroll
    for (int p = 0; p < 6; ++p)
      #pragma unroll
      for (int ni = 0; ni < NI; ++ni)
        acc[ni][PG[p]] = __builtin_amdgcn_mfma_f32_16x16x32_bf16(
            wf[p], xf[PJ[p]][ni], acc[ni][PG[p]], 0, 0, 0);
  };

  bf16x8 wfA[6], wfB[6];
  wfld(wfA, 0);
  __syncthreads();

  #pragma unroll
  for (int ec = 0; ec < 10; ec += 2) {
    wfld(wfB, ec + 1);
    compute(wfA, ec);
    if (ec + 2 < 10) wfld(wfA, ec + 2);
    compute(wfB, ec + 1);
  }

  const float* biases[3] = {b1, b2, b3};
  float4 bv[3];
  #pragma unroll
  for (int g = 0; g < 3; ++g)
    bv[g] = *reinterpret_cast<const float4*>(biases[g] + w * 16 + quad * 4);

  #pragma unroll
  for (int ni = 0; ni < NI; ++ni) {
    #pragma unroll
    for (int g = 0; g < 3; ++g) {
      float p = 0.f;
      #pragma unroll
      for (int r = 0; r < 4; ++r) {
        float y = fmaxf(acc[ni][g][r] + bv[g][r], 0.f);
        p += y * y;
      }
      p += __shfl_xor(p, 16);
      p += __shfl_xor(p, 32);
      if (lane < 16) psq[(w * 3 + g) * NR + ni * 16 + lrow] = p;
    }
  }
  __syncthreads();

  #pragma unroll
  for (int ni = 0; ni < NI; ++ni) {
    int row = ni * 16 + lrow;
    int l = l0 + row;
    if (l < L) {
      #pragma unroll
      for (int g = 0; g < 3; ++g) {
        float ssq = 0.f;
        #pragma unroll
        for (int wv = 0; wv < 8; ++wv) ssq += psq[(wv * 3 + g) * NR + row];
        float inv = 1.0f / (sqrtf(ssq) + 1e-13f);
        unsigned int pk[2];
        #pragma unroll
        for (int h = 0; h < 2; ++h) {
          float y0 = fmaxf(acc[ni][g][2 * h + 0] + bv[g][2 * h + 0], 0.f) * inv;
          float y1 = fmaxf(acc[ni][g][2 * h + 1] + bv[g][2 * h + 1], 0.f) * inv;
          pk[h] = (unsigned int)f2bf(y0) | ((unsigned int)f2bf(y1) << 16);
        }
        unsigned short* op = out + ((size_t)(g * 128 + b) * L + l) * 128 +
                             w * 16 + quad * 4;
        *reinterpret_cast<uint2*>(op) = make_uint2(pk[0], pk[1]);
      }
    }
  }
}

// blocks 0..1023: doc (b=bi>>3, l0=(bi&7)*32); 1024..1151: query (b=bi-1024)
__global__ __launch_bounds__(512, 4) void conv_all(
    const float* __restrict__ qemb, const float* __restrict__ demb,
    const unsigned short* __restrict__ wt2,
    const float* __restrict__ b1, const float* __restrict__ b2,
    const float* __restrict__ b3,
    unsigned short* __restrict__ qn, unsigned short* __restrict__ dn) {
  __shared__ unsigned short As[34 * AS_STRIDE];
  __shared__ float psq[8 * 3 * 32];
  const int bi = blockIdx.x;
  if (bi < 1024)
    conv_body<2>(As, psq, demb + (size_t)(bi >> 3) * 256 * 300, 256,
                 (bi & 7) * 32, bi >> 3, wt2, b1, b2, b3, dn);
  else
    conv_body<2>(As, psq, qemb + (size_t)(bi - 1024) * 30 * 300, 30,
                 0, bi - 1024, wt2, b1, b2, b3, qn);
}

// One wave per (tg, chunk, b): grid (24,128). R4-proven body; partials go
// out as RELAXED AGENT stores (sc1, coherence point — no fence needed);
// release = vmcnt(0) + relaxed agent inc; 24th arrival reads via relaxed
// agent loads and finishes out[b]. NO __threadfence anywhere (R8/R9: the
// per-block device fence's L2 writeback was ~180us + L2 thrash).
__global__ __launch_bounds__(64) void pool_finish(
    const unsigned short* __restrict__ qn, const unsigned short* __restrict__ dn,
    const float* __restrict__ qmask, const float* __restrict__ dmask,
    const float* __restrict__ dw,
    float* __restrict__ pkq8, unsigned int* __restrict__ cnt,
    float* __restrict__ out) {
  // exp(NEGC_k*(cm-MU_k)^2) = exp2(fma(w_k, cm - 2MU_k, NEGC_k*MU_k^2)),
  // w_k = NEGC_k*cm. k=0: NEGC0=-721347.52 (sigma 1e-3); k>=1: -72.134752.
  const float A2[11] = {2.0f, 1.8f, 1.4f, 1.0f, 0.6f, 0.2f,
                        -0.2f, -0.6f, -1.0f, -1.4f, -1.8f};
  const float CC[11] = {-721347.52f, -58.429149f, -35.346028f, -18.033688f,
                        -6.4921277f, -0.72134752f, -0.72134752f, -6.4921277f,
                        -18.033688f, -35.346028f, -58.429149f};
  const int tg    = blockIdx.x >> 3;
  const int chunk = blockIdx.x & 7;
  const int b     = blockIdx.y;
  const int lane  = threadIdx.x;
  const int quad  = lane >> 4, l15 = lane & 15;
  const int d0    = chunk * 32;

  const unsigned short* dslab = dn + (size_t)(tg * 128 + b) * 256 * 128;

  bf16x8 aD[2][4];
  #pragma unroll
  for (int mi = 0; mi < 2; ++mi)
    #pragma unroll
    for (int kt = 0; kt < 4; ++kt)
      aD[mi][kt] = *reinterpret_cast<const bf16x8*>(
          dslab + (size_t)(d0 + mi * 16 + l15) * 128 + kt * 32 + quad * 8);

  float dmv[2][4];
  #pragma unroll
  for (int mi = 0; mi < 2; ++mi)
    #pragma unroll
    for (int r = 0; r < 4; ++r)
      dmv[mi][r] = dmask[b * 256 + d0 + mi * 16 + quad * 4 + r];

  float qmv[2];
  qmv[0] = qmask[b * 30 + l15];
  qmv[1] = (16 + l15 < 30) ? qmask[b * 30 + 16 + l15] : 0.0f;

  #pragma unroll 1
  for (int ig = 0; ig < 3; ++ig) {
    const unsigned short* qslab = qn + (size_t)(ig * 128 + b) * 30 * 128;

    bf16x8 bQ[2][4];
    #pragma unroll
    for (int ni = 0; ni < 2; ++ni)
      #pragma unroll
      for (int kt = 0; kt < 4; ++kt)
        bQ[ni][kt] = *reinterpret_cast<const bf16x8*>(
            qslab + (size_t)(ni * 16 + l15) * 128 + kt * 32 + quad * 8);

    f32x4 acc[2][2];
    #pragma unroll
    for (int mi = 0; mi < 2; ++mi)
      #pragma unroll
      for (int ni = 0; ni < 2; ++ni) acc[mi][ni] = (f32x4){0.f, 0.f, 0.f, 0.f};

    #pragma unroll
    for (int kt = 0; kt < 4; ++kt)
      #pragma unroll
      for (int mi = 0; mi < 2; ++mi)
        #pragma unroll
        for (int ni = 0; ni < 2; ++ni)
          acc[mi][ni] = __builtin_amdgcn_mfma_f32_16x16x32_bf16(
              aD[mi][kt], bQ[ni][kt], acc[mi][ni], 0, 0, 0);

    float feat[2][11];
    #pragma unroll
    for (int ni = 0; ni < 2; ++ni)
      #pragma unroll
      for (int kk = 0; kk < 11; ++kk) feat[ni][kk] = 0.0f;

    #pragma unroll
    for (int mi = 0; mi < 2; ++mi) {
      #pragma unroll
      for (int r = 0; r < 4; ++r) {
        #pragma unroll
        for (int ni = 0; ni < 2; ++ni) {
          float m  = qmv[ni] * dmv[mi][r];
          float cm = acc[mi][ni][r] * m;
          float w0 = cm * -721347.52f;
          float w1c = cm * -72.134752f;
          #pragma unroll
          for (int kk = 0; kk < 11; ++kk) {
            float wk = (kk == 0) ? w0 : w1c;
            float e = EXP2F(fmaf(wk, cm - A2[kk], CC[kk]));
            feat[ni][kk] += e * m;
          }
        }
      }
    }

    #pragma unroll
    for (int ni = 0; ni < 2; ++ni)
      #pragma unroll
      for (int kk = 0; kk < 11; ++kk) {
        float v = feat[ni][kk];
        v += __shfl_xor(v, 16);
        v += __shfl_xor(v, 32);
        feat[ni][kk] = v;
      }

    if (quad == 0) {
      const int pair = ig * 3 + tg;
      #pragma unroll
      for (int ni = 0; ni < 2; ++ni) {
        int q = ni * 16 + l15;
        if (q < 30) {
          float* p = pkq8 + (((size_t)(chunk * 9 + pair) * 128 + b) * 30 + q) * 11;
          #pragma unroll
          for (int kk = 0; kk < 11; ++kk)
            __hip_atomic_store(p + kk, feat[ni][kk],
                               __ATOMIC_RELAXED, __HIP_MEMORY_SCOPE_AGENT);
        }
      }
    }
  }

  // ---- release: sc1 stores acknowledged at coherence point, then count ----
  asm volatile("s_waitcnt vmcnt(0)" ::: "memory");
  unsigned int prev0 = 0;
  if (lane == 0)
    prev0 = __hip_atomic_fetch_add(&cnt[b], 1u,
                                   __ATOMIC_RELAXED, __HIP_MEMORY_SCOPE_AGENT);
  unsigned int prev = (unsigned int)__shfl((int)prev0, 0);
  if (prev == 23u) {                     // all 24 (tg,chunk) blocks done
    float s = 0.0f;
    for (int idx = lane; idx < 330; idx += 64) {
      int q = idx / 11, kk = idx % 11;
      float qm = qmask[b * 30 + q] * 0.01f;
      #pragma unroll
      for (int pair = 0; pair < 9; ++pair) {
        float v = 0.f;
        #pragma unroll
        for (int c = 0; c < 8; ++c)
          v += __hip_atomic_load(
              &pkq8[((size_t)(c * 9 + pair) * 128 + b) * 330 + idx],
              __ATOMIC_RELAXED, __HIP_MEMORY_SCOPE_AGENT);
        s += __logf(fmaxf(v, 1e-10f)) * qm * dw[pair * 11 + kk];
      }
    }
    s += __shfl_xor(s, 1);  s += __shfl_xor(s, 2);  s += __shfl_xor(s, 4);
    s += __shfl_xor(s, 8);  s += __shfl_xor(s, 16); s += __shfl_xor(s, 32);
    if (lane == 0) out[b] = s;
  }
}

extern "C" void kernel_launch(void* const* d_in, const int* in_sizes, int n_in,
                              void* d_out, int out_size, void* d_ws, size_t ws_size,
                              hipStream_t stream) {
  const float* qemb  = (const float*)d_in[0];
  const float* demb  = (const float*)d_in[1];
  const float* qmask = (const float*)d_in[2];
  const float* dmask = (const float*)d_in[3];
  const float* w1 = (const float*)d_in[4];
  const float* b1 = (const float*)d_in[5];
  const float* w2 = (const float*)d_in[6];
  const float* b2 = (const float*)d_in[7];
  const float* w3 = (const float*)d_in[8];
  const float* b3 = (const float*)d_in[9];
  const float* dw = (const float*)d_in[10];

  unsigned short* ws  = (unsigned short*)d_ws;
  unsigned short* wt2 = ws;                       // 245760 shorts
  float*          pkq8 = (float*)(ws + 245760);   // 3041280 f32 (12.2MB)
  unsigned int*   cnt  = (unsigned int*)(pkq8 + 3041280);  // 128 u32
  unsigned short* qn  = ws + 12042240;            // 1474560 shorts
  unsigned short* dn  = ws + 13516800;            // 12582912 shorts
  float* out = (float*)d_out;

  prep_w<<<960, 256, 0, stream>>>(w1, w2, w3, wt2, cnt);
  conv_all<<<1152, 512, 0, stream>>>(qemb, demb, wt2, b1, b2, b3, qn, dn);
  pool_finish<<<dim3(24, 128), 64, 0, stream>>>(qn, dn, qmask, dmask, dw,
                                                pkq8, cnt, out);
}

// Round 11
// 166.172 us; speedup vs baseline: 1.8174x; 1.8174x over previous
//
#include <hip/hip_runtime.h>
#include <math.h>

// Conv-KNRM on MI355X. B=128, QLEN=30, DLEN=256, EMB=300, C=128.
//
// R11: 3 dispatches, ZERO cross-block data communication in pool.
// R8/R9/R10 proved every in-kernel cross-XCD coherence mechanism for the
// 12.2MB partials costs ~170-190us (atomicAdd: 95MB line traffic; plain+
// threadfence: serialized L2 writebacks; sc1 write-through: 95MB partial-
// line HBM writes). Only the kernel boundary is cheap coherence. So the
// pool keeps ALL partials in LDS: unit = (tg,b) = one block, 8 subwaves
// x 32 d-rows streamed in 16-row chunks (R7-validated math), psum in LDS,
// in-block log/qmask/dense-dot, one atomicAdd(out+b) per unit (384 total,
// R6-validated numerically). R6's spill (LB(512,1) cap 128 < ~150 live;
// FETCH/WRITE spill signature, 57us) fixed by launch_bounds(512,2)
// (VGPR cap >=256) + the 16-row-chunk body (live ~100).
//
//   prep_w     : weights -> wt2 bf16 frag-order [plane6][cb8][ec10][lane64][8]
//   conv_all   : 1152 blocks x 512 thr; NI=2; fp32->bf16 fused staging;
//                A=w frags global (compiler wfA/wfB prefetch), B=x LDS;
//                bias+relu+L2norm -> bf16 [g][b][l][c]. (R4-proven: VGPR 40)
//   pool_final : 384 blocks x 512 thr; block = (tg,b); MFMA cos + RBF x11;
//                quad shfl d-sum -> psum[3][8][330] LDS; finish in-block;
//                atomicAdd(out+b). out zeroed by harness memset.
//
// ws (shorts): wt2@0 (245760) | qn@12042240 (1474560) | dn@13516800 (12582912)

typedef __bf16 bf16x8 __attribute__((ext_vector_type(8)));
typedef float f32x4 __attribute__((ext_vector_type(4)));

#if __has_builtin(__builtin_amdgcn_exp2f)
#define EXP2F(x) __builtin_amdgcn_exp2f(x)
#else
#define EXP2F(x) exp2f(x)
#endif

#define AS_STRIDE 344  // shorts; 688 B row: 2-way b128 (free), 16B-aligned

static __device__ __forceinline__ unsigned short f2bf(float f) {
  union { float f; unsigned int u; } v; v.f = f;
  unsigned int r = v.u + 0x7FFFu + ((v.u >> 16) & 1u);  // RNE
  return (unsigned short)(r >> 16);
}

// weights -> frag order (exactly 960*256 = 245760 elems)
__global__ __launch_bounds__(256) void prep_w(
    const float* __restrict__ w1, const float* __restrict__ w2,
    const float* __restrict__ w3, unsigned short* __restrict__ wt2) {
  int idx = blockIdx.x * 256 + threadIdx.x;
  if (idx >= 245760) return;
  int jj   = idx & 7;
  int lane = (idx >> 3) & 63;
  int ec   = (idx >> 9) % 10;
  int cb   = (idx / 5120) & 7;
  int p    = idx / 40960;
  const float* w; int k, jt;
  if (p == 0)      { w = w1; k = 1; jt = 0; }
  else if (p <= 2) { w = w2; k = 2; jt = p - 1; }
  else             { w = w3; k = 3; jt = p - 3; }
  int c = cb * 16 + (lane & 15);
  int e = ec * 32 + (lane >> 4) * 8 + jj;
  float v = (e < 300) ? w[(c * 300 + e) * k + jt] : 0.0f;
  wt2[idx] = f2bf(v);
}

// Wave tile: NI*16 l-rows x 48 ch (cb=w: 16 ch in each of 3 grams).
// A-operand = weights (frag-order global, reg-dbuf prefetch), B = x (LDS,
// fp32->bf16 packed during staging). R4-proven (VGPR 40, no spills).
// plane p -> (j,g): {0,0},{0,1},{1,1},{0,2},{1,2},{2,2}
template<int NI>
__device__ __forceinline__ void conv_body(
    unsigned short* As, float* psq,  // psq[8][3][NI*16]
    const float* __restrict__ xs, int L, int l0, int b,
    const unsigned short* __restrict__ wt2,
    const float* __restrict__ b1, const float* __restrict__ b2,
    const float* __restrict__ b3,
    unsigned short* __restrict__ out) {
  constexpr int ROWS = NI * 16 + 2;
  constexpr int NR = NI * 16;
  const int t = threadIdx.x;
  const int w = __builtin_amdgcn_readfirstlane(t >> 6);  // cb 0..7
  const int lane = t & 63;
  const int quad = lane >> 4, lrow = lane & 15;

  // stage A: fp32 -> bf16 pack, ROWS x 40 uint4 (tail e>=296 zero-guarded)
  for (int idx = t; idx < ROWS * 40; idx += 512) {
    int r = idx / 40, c = idx % 40;
    int l = l0 + r;
    int e = c * 8;
    float4 a = make_float4(0.f, 0.f, 0.f, 0.f);
    float4 cc = make_float4(0.f, 0.f, 0.f, 0.f);
    if (l < L) {
      const float* src = xs + (size_t)l * 300;
      if (e < 300)     a  = *reinterpret_cast<const float4*>(src + e);
      if (e + 4 < 300) cc = *reinterpret_cast<const float4*>(src + e + 4);
    }
    uint4 o;
    o.x = (unsigned int)f2bf(a.x) | ((unsigned int)f2bf(a.y) << 16);
    o.y = (unsigned int)f2bf(a.z) | ((unsigned int)f2bf(a.w) << 16);
    o.z = (unsigned int)f2bf(cc.x) | ((unsigned int)f2bf(cc.y) << 16);
    o.w = (unsigned int)f2bf(cc.z) | ((unsigned int)f2bf(cc.w) << 16);
    *reinterpret_cast<uint4*>(&As[r * AS_STRIDE + c * 8]) = o;
  }

  f32x4 acc[NI][3];
  #pragma unroll
  for (int ni = 0; ni < NI; ++ni)
    #pragma unroll
    for (int g = 0; g < 3; ++g) acc[ni][g] = (f32x4){0.f, 0.f, 0.f, 0.f};

  const unsigned short* wl = wt2 + (size_t)lane * 8;

  auto wfld = [&](bf16x8* dst, int ec) {
    #pragma unroll
    for (int p = 0; p < 6; ++p)
      dst[p] = *reinterpret_cast<const bf16x8*>(
          wl + ((((p * 8 + w) * 10 + ec) << 9)));
  };

  auto compute = [&](const bf16x8* wf, int ec) {
    bf16x8 xf[3][NI];
    #pragma unroll
    for (int j = 0; j < 3; ++j)
      #pragma unroll
      for (int ni = 0; ni < NI; ++ni)
        xf[j][ni] = *reinterpret_cast<const bf16x8*>(
            &As[(ni * 16 + lrow + j) * AS_STRIDE + ec * 32 + quad * 8]);
    const int PJ[6] = {0, 0, 1, 0, 1, 2};
    const int PG[6] = {0, 1, 1, 2, 2, 2};
    #pragma unroll
    for (int p = 0; p < 6; ++p)
      #pragma unroll
      for (int ni = 0; ni < NI; ++ni)
        acc[ni][PG[p]] = __builtin_amdgcn_mfma_f32_16x16x32_bf16(
            wf[p], xf[PJ[p]][ni], acc[ni][PG[p]], 0, 0, 0);
  };

  bf16x8 wfA[6], wfB[6];
  wfld(wfA, 0);
  __syncthreads();

  #pragma unroll
  for (int ec = 0; ec < 10; ec += 2) {
    wfld(wfB, ec + 1);
    compute(wfA, ec);
    if (ec + 2 < 10) wfld(wfA, ec + 2);
    compute(wfB, ec + 1);
  }

  const float* biases[3] = {b1, b2, b3};
  float4 bv[3];
  #pragma unroll
  for (int g = 0; g < 3; ++g)
    bv[g] = *reinterpret_cast<const float4*>(biases[g] + w * 16 + quad * 4);

  #pragma unroll
  for (int ni = 0; ni < NI; ++ni) {
    #pragma unroll
    for (int g = 0; g < 3; ++g) {
      float p = 0.f;
      #pragma unroll
      for (int r = 0; r < 4; ++r) {
        float y = fmaxf(acc[ni][g][r] + bv[g][r], 0.f);
        p += y * y;
      }
      p += __shfl_xor(p, 16);
      p += __shfl_xor(p, 32);
      if (lane < 16) psq[(w * 3 + g) * NR + ni * 16 + lrow] = p;
    }
  }
  __syncthreads();

  #pragma unroll
  for (int ni = 0; ni < NI; ++ni) {
    int row = ni * 16 + lrow;
    int l = l0 + row;
    if (l < L) {
      #pragma unroll
      for (int g = 0; g < 3; ++g) {
        float ssq = 0.f;
        #pragma unroll
        for (int wv = 0; wv < 8; ++wv) ssq += psq[(wv * 3 + g) * NR + row];
        float inv = 1.0f / (sqrtf(ssq) + 1e-13f);
        unsigned int pk[2];
        #pragma unroll
        for (int h = 0; h < 2; ++h) {
          float y0 = fmaxf(acc[ni][g][2 * h + 0] + bv[g][2 * h + 0], 0.f) * inv;
          float y1 = fmaxf(acc[ni][g][2 * h + 1] + bv[g][2 * h + 1], 0.f) * inv;
          pk[h] = (unsigned int)f2bf(y0) | ((unsigned int)f2bf(y1) << 16);
        }
        unsigned short* op = out + ((size_t)(g * 128 + b) * L + l) * 128 +
                             w * 16 + quad * 4;
        *reinterpret_cast<uint2*>(op) = make_uint2(pk[0], pk[1]);
      }
    }
  }
}

// blocks 0..1023: doc (b=bi>>3, l0=(bi&7)*32); 1024..1151: query (b=bi-1024)
__global__ __launch_bounds__(512, 4) void conv_all(
    const float* __restrict__ qemb, const float* __restrict__ demb,
    const unsigned short* __restrict__ wt2,
    const float* __restrict__ b1, const float* __restrict__ b2,
    const float* __restrict__ b3,
    unsigned short* __restrict__ qn, unsigned short* __restrict__ dn) {
  __shared__ unsigned short As[34 * AS_STRIDE];
  __shared__ float psq[8 * 3 * 32];
  const int bi = blockIdx.x;
  if (bi < 1024)
    conv_body<2>(As, psq, demb + (size_t)(bi >> 3) * 256 * 300, 256,
                 (bi & 7) * 32, bi >> 3, wt2, b1, b2, b3, dn);
  else
    conv_body<2>(As, psq, qemb + (size_t)(bi - 1024) * 30 * 300, 30,
                 0, bi - 1024, wt2, b1, b2, b3, qn);
}

// 384 blocks x 512 thr; block = unit (tg,b). 8 subwaves x 32 d-rows,
// streamed in 16-row chunks (R7-validated body: aD[4]=16+acc[2]=8 live).
// All partials in LDS psum[3][8][330]; in-block finish; atomicAdd(out+b).
// launch_bounds(512,2): VGPR cap >=256 -> no spill (R6's failure mode).
__global__ __launch_bounds__(512, 2) void pool_final(
    const unsigned short* __restrict__ qn, const unsigned short* __restrict__ dn,
    const float* __restrict__ qmask, const float* __restrict__ dmask,
    const float* __restrict__ dw, float* __restrict__ out) {
  // exp(NEGC_k*(cm-MU_k)^2) = exp2(fma(w_k, cm - 2MU_k, NEGC_k*MU_k^2)),
  // w_k = NEGC_k*cm. k=0: NEGC0=-721347.52 (sigma 1e-3); k>=1: -72.134752.
  const float A2[11] = {2.0f, 1.8f, 1.4f, 1.0f, 0.6f, 0.2f,
                        -0.2f, -0.6f, -1.0f, -1.4f, -1.8f};
  const float CC[11] = {-721347.52f, -58.429149f, -35.346028f, -18.033688f,
                        -6.4921277f, -0.72134752f, -0.72134752f, -6.4921277f,
                        -18.033688f, -35.346028f, -58.429149f};
  __shared__ float psum[3][8][330];  // [ig][subwave][q*11+kk]
  __shared__ float wsum[8];
  const int t = threadIdx.x;
  const int wv   = t >> 6;          // subwave 0..7: d rows [wv*32, wv*32+32)
  const int lane = t & 63;
  const int quad = lane >> 4, l15 = lane & 15;
  const int u  = blockIdx.x;        // 0..383
  const int tg = u >> 7;            // doc gram 0..2
  const int b  = u & 127;

  const unsigned short* dslab = dn + (size_t)(tg * 128 + b) * 256 * 128;
  float qmv[2];
  qmv[0] = qmask[b * 30 + l15];
  qmv[1] = (16 + l15 < 30) ? qmask[b * 30 + 16 + l15] : 0.0f;

  #pragma unroll 1
  for (int ig = 0; ig < 3; ++ig) {
    const unsigned short* qslab = qn + (size_t)(ig * 128 + b) * 30 * 128;
    bf16x8 bQ[2][4];
    #pragma unroll
    for (int ni = 0; ni < 2; ++ni)
      #pragma unroll
      for (int kt = 0; kt < 4; ++kt)
        bQ[ni][kt] = *reinterpret_cast<const bf16x8*>(
            qslab + (size_t)(ni * 16 + l15) * 128 + kt * 32 + quad * 8);

    float feat[2][11];
    #pragma unroll
    for (int ni = 0; ni < 2; ++ni)
      #pragma unroll
      for (int kk = 0; kk < 11; ++kk) feat[ni][kk] = 0.0f;

    // stream the subwave's 32 d-rows in 16-row chunks (low live set)
    #pragma unroll 1
    for (int c = 0; c < 2; ++c) {
      const int d0 = wv * 32 + c * 16;
      bf16x8 aD[4];
      #pragma unroll
      for (int kt = 0; kt < 4; ++kt)
        aD[kt] = *reinterpret_cast<const bf16x8*>(
            dslab + (size_t)(d0 + l15) * 128 + kt * 32 + quad * 8);
      float dmv[4];
      #pragma unroll
      for (int r = 0; r < 4; ++r)
        dmv[r] = dmask[b * 256 + d0 + quad * 4 + r];

      f32x4 acc[2];
      acc[0] = (f32x4){0.f, 0.f, 0.f, 0.f};
      acc[1] = (f32x4){0.f, 0.f, 0.f, 0.f};
      #pragma unroll
      for (int kt = 0; kt < 4; ++kt)
        #pragma unroll
        for (int ni = 0; ni < 2; ++ni)
          acc[ni] = __builtin_amdgcn_mfma_f32_16x16x32_bf16(
              aD[kt], bQ[ni][kt], acc[ni], 0, 0, 0);

      #pragma unroll
      for (int r = 0; r < 4; ++r) {
        #pragma unroll
        for (int ni = 0; ni < 2; ++ni) {
          float m  = qmv[ni] * dmv[r];
          float cm = acc[ni][r] * m;
          float w0 = cm * -721347.52f;
          float w1c = cm * -72.134752f;
          #pragma unroll
          for (int kk = 0; kk < 11; ++kk) {
            float wk = (kk == 0) ? w0 : w1c;
            float e = EXP2F(fmaf(wk, cm - A2[kk], CC[kk]));
            feat[ni][kk] += e * m;
          }
        }
      }
    }

    // sum over quads (d within the subwave's 32 rows)
    #pragma unroll
    for (int ni = 0; ni < 2; ++ni)
      #pragma unroll
      for (int kk = 0; kk < 11; ++kk) {
        float v = feat[ni][kk];
        v += __shfl_xor(v, 16);
        v += __shfl_xor(v, 32);
        feat[ni][kk] = v;
      }

    if (quad == 0) {
      #pragma unroll
      for (int ni = 0; ni < 2; ++ni) {
        int q = ni * 16 + l15;
        if (q < 30) {
          #pragma unroll
          for (int kk = 0; kk < 11; ++kk)
            psum[ig][wv][q * 11 + kk] = feat[ni][kk];
        }
      }
    }
  }
  __syncthreads();

  // block finish: sum 8 subwaves, log, qmask, dense-dot, one atomicAdd
  float s = 0.0f;
  if (t < 330) {
    int q = t / 11, kk = t % 11;
    float qm = qmask[b * 30 + q] * 0.01f;
    #pragma unroll
    for (int ig = 0; ig < 3; ++ig) {
      float v = 0.f;
      #pragma unroll
      for (int sub = 0; sub < 8; ++sub) v += psum[ig][sub][t];
      s += __logf(fmaxf(v, 1e-10f)) * qm * dw[(ig * 3 + tg) * 11 + kk];
    }
  }
  s += __shfl_xor(s, 1);  s += __shfl_xor(s, 2);  s += __shfl_xor(s, 4);
  s += __shfl_xor(s, 8);  s += __shfl_xor(s, 16); s += __shfl_xor(s, 32);
  if (lane == 0) wsum[wv] = s;
  __syncthreads();
  if (t == 0)
    atomicAdd(out + b, wsum[0] + wsum[1] + wsum[2] + wsum[3] +
                       wsum[4] + wsum[5] + wsum[6] + wsum[7]);
}

extern "C" void kernel_launch(void* const* d_in, const int* in_sizes, int n_in,
                              void* d_out, int out_size, void* d_ws, size_t ws_size,
                              hipStream_t stream) {
  const float* qemb  = (const float*)d_in[0];
  const float* demb  = (const float*)d_in[1];
  const float* qmask = (const float*)d_in[2];
  const float* dmask = (const float*)d_in[3];
  const float* w1 = (const float*)d_in[4];
  const float* b1 = (const float*)d_in[5];
  const float* w2 = (const float*)d_in[6];
  const float* b2 = (const float*)d_in[7];
  const float* w3 = (const float*)d_in[8];
  const float* b3 = (const float*)d_in[9];
  const float* dw = (const float*)d_in[10];

  unsigned short* ws  = (unsigned short*)d_ws;
  unsigned short* wt2 = ws;                       // 245760 shorts
  unsigned short* qn  = ws + 12042240;            // 1474560 shorts
  unsigned short* dn  = ws + 13516800;            // 12582912 shorts
  float* out = (float*)d_out;

  prep_w<<<960, 256, 0, stream>>>(w1, w2, w3, wt2);
  conv_all<<<1152, 512, 0, stream>>>(qemb, demb, wt2, b1, b2, b3, qn, dn);
  pool_final<<<384, 512, 0, stream>>>(qn, dn, qmask, dmask, dw, out);
}

// Round 12
// 163.816 us; speedup vs baseline: 1.8436x; 1.0144x over previous
//
#include <hip/hip_runtime.h>
#include <math.h>

// Conv-KNRM on MI355X. B=128, QLEN=30, DLEN=256, EMB=300, C=128.
//
// R12: model revision from R4..R11 fits: total = SUM(kernel times) + ~78us
// FIXED harness overhead (dispatch count irrelevant: R6 105+78, R7 198+76,
// R8 237+76, R10 222+80, R11 88+78, R4 86+78). So minimize kernel-time sum.
// R11 back-solve: pool_final ~40us; cause: aD (dn slab) re-loaded inside
// the ig loop -> dn traffic 3x24MB=72MB. R12 hoists the d-chunk (c) loop
// OUTSIDE ig: dn read exactly once (24MB); bQ re-read per (c,ig) is 2x qn
// = 1.4MB L2/L3-resident (free). Live set kept ~100 regs (aD[4]=16 not
// aD[2][4]=32; feat accumulated into LDS psum across c) to avoid R6's
// spill mode (~140 live vs 128 cap).
//
//   prep_w     : weights -> wt2 bf16 frag-order [plane6][cb8][ec10][lane64][8]
//   conv_all   : 1152 blocks x 512 thr; NI=2; fp32->bf16 fused staging;
//                A=w frags global (compiler wfA/wfB prefetch), B=x LDS;
//                bias+relu+L2norm -> bf16 [g][b][l][c]. (R4-proven: VGPR 40)
//   pool_final : 384 blocks x 512 thr; block = (tg,b); c-outer/ig-inner;
//                MFMA cos + RBF x11; quad shfl d-sum -> psum[3][8][330] LDS
//                (write on c=0, add on c=1); in-block log/qmask/dense-dot;
//                atomicAdd(out+b). out zeroed by harness memset.
//
// ws (shorts): wt2@0 (245760) | qn@12042240 (1474560) | dn@13516800 (12582912)

typedef __bf16 bf16x8 __attribute__((ext_vector_type(8)));
typedef float f32x4 __attribute__((ext_vector_type(4)));

#if __has_builtin(__builtin_amdgcn_exp2f)
#define EXP2F(x) __builtin_amdgcn_exp2f(x)
#else
#define EXP2F(x) exp2f(x)
#endif

#define AS_STRIDE 344  // shorts; 688 B row: 2-way b128 (free), 16B-aligned

static __device__ __forceinline__ unsigned short f2bf(float f) {
  union { float f; unsigned int u; } v; v.f = f;
  unsigned int r = v.u + 0x7FFFu + ((v.u >> 16) & 1u);  // RNE
  return (unsigned short)(r >> 16);
}

// weights -> frag order (exactly 960*256 = 245760 elems)
__global__ __launch_bounds__(256) void prep_w(
    const float* __restrict__ w1, const float* __restrict__ w2,
    const float* __restrict__ w3, unsigned short* __restrict__ wt2) {
  int idx = blockIdx.x * 256 + threadIdx.x;
  if (idx >= 245760) return;
  int jj   = idx & 7;
  int lane = (idx >> 3) & 63;
  int ec   = (idx >> 9) % 10;
  int cb   = (idx / 5120) & 7;
  int p    = idx / 40960;
  const float* w; int k, jt;
  if (p == 0)      { w = w1; k = 1; jt = 0; }
  else if (p <= 2) { w = w2; k = 2; jt = p - 1; }
  else             { w = w3; k = 3; jt = p - 3; }
  int c = cb * 16 + (lane & 15);
  int e = ec * 32 + (lane >> 4) * 8 + jj;
  float v = (e < 300) ? w[(c * 300 + e) * k + jt] : 0.0f;
  wt2[idx] = f2bf(v);
}

// Wave tile: NI*16 l-rows x 48 ch (cb=w: 16 ch in each of 3 grams).
// A-operand = weights (frag-order global, reg-dbuf prefetch), B = x (LDS,
// fp32->bf16 packed during staging). R4-proven (VGPR 40, no spills).
// plane p -> (j,g): {0,0},{0,1},{1,1},{0,2},{1,2},{2,2}
template<int NI>
__device__ __forceinline__ void conv_body(
    unsigned short* As, float* psq,  // psq[8][3][NI*16]
    const float* __restrict__ xs, int L, int l0, int b,
    const unsigned short* __restrict__ wt2,
    const float* __restrict__ b1, const float* __restrict__ b2,
    const float* __restrict__ b3,
    unsigned short* __restrict__ out) {
  constexpr int ROWS = NI * 16 + 2;
  constexpr int NR = NI * 16;
  const int t = threadIdx.x;
  const int w = __builtin_amdgcn_readfirstlane(t >> 6);  // cb 0..7
  const int lane = t & 63;
  const int quad = lane >> 4, lrow = lane & 15;

  // stage A: fp32 -> bf16 pack, ROWS x 40 uint4 (tail e>=296 zero-guarded)
  for (int idx = t; idx < ROWS * 40; idx += 512) {
    int r = idx / 40, c = idx % 40;
    int l = l0 + r;
    int e = c * 8;
    float4 a = make_float4(0.f, 0.f, 0.f, 0.f);
    float4 cc = make_float4(0.f, 0.f, 0.f, 0.f);
    if (l < L) {
      const float* src = xs + (size_t)l * 300;
      if (e < 300)     a  = *reinterpret_cast<const float4*>(src + e);
      if (e + 4 < 300) cc = *reinterpret_cast<const float4*>(src + e + 4);
    }
    uint4 o;
    o.x = (unsigned int)f2bf(a.x) | ((unsigned int)f2bf(a.y) << 16);
    o.y = (unsigned int)f2bf(a.z) | ((unsigned int)f2bf(a.w) << 16);
    o.z = (unsigned int)f2bf(cc.x) | ((unsigned int)f2bf(cc.y) << 16);
    o.w = (unsigned int)f2bf(cc.z) | ((unsigned int)f2bf(cc.w) << 16);
    *reinterpret_cast<uint4*>(&As[r * AS_STRIDE + c * 8]) = o;
  }

  f32x4 acc[NI][3];
  #pragma unroll
  for (int ni = 0; ni < NI; ++ni)
    #pragma unroll
    for (int g = 0; g < 3; ++g) acc[ni][g] = (f32x4){0.f, 0.f, 0.f, 0.f};

  const unsigned short* wl = wt2 + (size_t)lane * 8;

  auto wfld = [&](bf16x8* dst, int ec) {
    #pragma unroll
    for (int p = 0; p < 6; ++p)
      dst[p] = *reinterpret_cast<const bf16x8*>(
          wl + ((((p * 8 + w) * 10 + ec) << 9)));
  };

  auto compute = [&](const bf16x8* wf, int ec) {
    bf16x8 xf[3][NI];
    #pragma unroll
    for (int j = 0; j < 3; ++j)
      #pragma unroll
      for (int ni = 0; ni < NI; ++ni)
        xf[j][ni] = *reinterpret_cast<const bf16x8*>(
            &As[(ni * 16 + lrow + j) * AS_STRIDE + ec * 32 + quad * 8]);
    const int PJ[6] = {0, 0, 1, 0, 1, 2};
    const int PG[6] = {0, 1, 1, 2, 2, 2};
    #pragma unroll
    for (int p = 0; p < 6; ++p)
      #pragma unroll
      for (int ni = 0; ni < NI; ++ni)
        acc[ni][PG[p]] = __builtin_amdgcn_mfma_f32_16x16x32_bf16(
            wf[p], xf[PJ[p]][ni], acc[ni][PG[p]], 0, 0, 0);
  };

  bf16x8 wfA[6], wfB[6];
  wfld(wfA, 0);
  __syncthreads();

  #pragma unroll
  for (int ec = 0; ec < 10; ec += 2) {
    wfld(wfB, ec + 1);
    compute(wfA, ec);
    if (ec + 2 < 10) wfld(wfA, ec + 2);
    compute(wfB, ec + 1);
  }

  const float* biases[3] = {b1, b2, b3};
  float4 bv[3];
  #pragma unroll
  for (int g = 0; g < 3; ++g)
    bv[g] = *reinterpret_cast<const float4*>(biases[g] + w * 16 + quad * 4);

  #pragma unroll
  for (int ni = 0; ni < NI; ++ni) {
    #pragma unroll
    for (int g = 0; g < 3; ++g) {
      float p = 0.f;
      #pragma unroll
      for (int r = 0; r < 4; ++r) {
        float y = fmaxf(acc[ni][g][r] + bv[g][r], 0.f);
        p += y * y;
      }
      p += __shfl_xor(p, 16);
      p += __shfl_xor(p, 32);
      if (lane < 16) psq[(w * 3 + g) * NR + ni * 16 + lrow] = p;
    }
  }
  __syncthreads();

  #pragma unroll
  for (int ni = 0; ni < NI; ++ni) {
    int row = ni * 16 + lrow;
    int l = l0 + row;
    if (l < L) {
      #pragma unroll
      for (int g = 0; g < 3; ++g) {
        float ssq = 0.f;
        #pragma unroll
        for (int wv = 0; wv < 8; ++wv) ssq += psq[(wv * 3 + g) * NR + row];
        float inv = 1.0f / (sqrtf(ssq) + 1e-13f);
        unsigned int pk[2];
        #pragma unroll
        for (int h = 0; h < 2; ++h) {
          float y0 = fmaxf(acc[ni][g][2 * h + 0] + bv[g][2 * h + 0], 0.f) * inv;
          float y1 = fmaxf(acc[ni][g][2 * h + 1] + bv[g][2 * h + 1], 0.f) * inv;
          pk[h] = (unsigned int)f2bf(y0) | ((unsigned int)f2bf(y1) << 16);
        }
        unsigned short* op = out + ((size_t)(g * 128 + b) * L + l) * 128 +
                             w * 16 + quad * 4;
        *reinterpret_cast<uint2*>(op) = make_uint2(pk[0], pk[1]);
      }
    }
  }
}

// blocks 0..1023: doc (b=bi>>3, l0=(bi&7)*32); 1024..1151: query (b=bi-1024)
__global__ __launch_bounds__(512, 4) void conv_all(
    const float* __restrict__ qemb, const float* __restrict__ demb,
    const unsigned short* __restrict__ wt2,
    const float* __restrict__ b1, const float* __restrict__ b2,
    const float* __restrict__ b3,
    unsigned short* __restrict__ qn, unsigned short* __restrict__ dn) {
  __shared__ unsigned short As[34 * AS_STRIDE];
  __shared__ float psq[8 * 3 * 32];
  const int bi = blockIdx.x;
  if (bi < 1024)
    conv_body<2>(As, psq, demb + (size_t)(bi >> 3) * 256 * 300, 256,
                 (bi & 7) * 32, bi >> 3, wt2, b1, b2, b3, dn);
  else
    conv_body<2>(As, psq, qemb + (size_t)(bi - 1024) * 30 * 300, 30,
                 0, bi - 1024, wt2, b1, b2, b3, qn);
}

// 384 blocks x 512 thr; block = unit (tg,b). Subwave wv owns d rows
// [wv*32, wv*32+32), streamed as 2 chunks of 16 (c loop OUTER). Per c:
// aD[4]+dmv loaded ONCE; inner ig loop reloads only bQ (qn is L2/L3-hot).
// dn read exactly once (24MB total vs R11's 72MB). psum accumulated in LDS
// across c (write c=0, add c=1). Live ~100 regs -> no spill at any cap.
__global__ __launch_bounds__(512, 2) void pool_final(
    const unsigned short* __restrict__ qn, const unsigned short* __restrict__ dn,
    const float* __restrict__ qmask, const float* __restrict__ dmask,
    const float* __restrict__ dw, float* __restrict__ out) {
  // exp(NEGC_k*(cm-MU_k)^2) = exp2(fma(w_k, cm - 2MU_k, NEGC_k*MU_k^2)),
  // w_k = NEGC_k*cm. k=0: NEGC0=-721347.52 (sigma 1e-3); k>=1: -72.134752.
  const float A2[11] = {2.0f, 1.8f, 1.4f, 1.0f, 0.6f, 0.2f,
                        -0.2f, -0.6f, -1.0f, -1.4f, -1.8f};
  const float CC[11] = {-721347.52f, -58.429149f, -35.346028f, -18.033688f,
                        -6.4921277f, -0.72134752f, -0.72134752f, -6.4921277f,
                        -18.033688f, -35.346028f, -58.429149f};
  __shared__ float psum[3][8][330];  // [ig][subwave][q*11+kk]
  __shared__ float wsum[8];
  const int t = threadIdx.x;
  const int wv   = t >> 6;          // subwave 0..7: d rows [wv*32, wv*32+32)
  const int lane = t & 63;
  const int quad = lane >> 4, l15 = lane & 15;
  const int u  = blockIdx.x;        // 0..383
  const int tg = u >> 7;            // doc gram 0..2
  const int b  = u & 127;

  const unsigned short* dslab = dn + (size_t)(tg * 128 + b) * 256 * 128;
  float qmv[2];
  qmv[0] = qmask[b * 30 + l15];
  qmv[1] = (16 + l15 < 30) ? qmask[b * 30 + 16 + l15] : 0.0f;

  // c OUTER: dn fragments for this 16-row chunk loaded once, reused for
  // all 3 query-grams (R11 reloaded them per ig -> 3x dn traffic).
  #pragma unroll 1
  for (int c = 0; c < 2; ++c) {
    const int d0 = wv * 32 + c * 16;
    bf16x8 aD[4];
    #pragma unroll
    for (int kt = 0; kt < 4; ++kt)
      aD[kt] = *reinterpret_cast<const bf16x8*>(
          dslab + (size_t)(d0 + l15) * 128 + kt * 32 + quad * 8);
    float dmv[4];
    #pragma unroll
    for (int r = 0; r < 4; ++r)
      dmv[r] = dmask[b * 256 + d0 + quad * 4 + r];

    #pragma unroll 1
    for (int ig = 0; ig < 3; ++ig) {
      const unsigned short* qslab = qn + (size_t)(ig * 128 + b) * 30 * 128;
      bf16x8 bQ[2][4];
      #pragma unroll
      for (int ni = 0; ni < 2; ++ni)
        #pragma unroll
        for (int kt = 0; kt < 4; ++kt)
          bQ[ni][kt] = *reinterpret_cast<const bf16x8*>(
              qslab + (size_t)(ni * 16 + l15) * 128 + kt * 32 + quad * 8);

      f32x4 acc[2];
      acc[0] = (f32x4){0.f, 0.f, 0.f, 0.f};
      acc[1] = (f32x4){0.f, 0.f, 0.f, 0.f};
      #pragma unroll
      for (int kt = 0; kt < 4; ++kt)
        #pragma unroll
        for (int ni = 0; ni < 2; ++ni)
          acc[ni] = __builtin_amdgcn_mfma_f32_16x16x32_bf16(
              aD[kt], bQ[ni][kt], acc[ni], 0, 0, 0);

      float feat[2][11];
      #pragma unroll
      for (int ni = 0; ni < 2; ++ni)
        #pragma unroll
        for (int kk = 0; kk < 11; ++kk) feat[ni][kk] = 0.0f;

      #pragma unroll
      for (int r = 0; r < 4; ++r) {
        #pragma unroll
        for (int ni = 0; ni < 2; ++ni) {
          float m  = qmv[ni] * dmv[r];
          float cm = acc[ni][r] * m;
          float w0 = cm * -721347.52f;
          float w1c = cm * -72.134752f;
          #pragma unroll
          for (int kk = 0; kk < 11; ++kk) {
            float wk = (kk == 0) ? w0 : w1c;
            float e = EXP2F(fmaf(wk, cm - A2[kk], CC[kk]));
            feat[ni][kk] += e * m;
          }
        }
      }

      // sum over quads (d within this 16-row chunk)
      #pragma unroll
      for (int ni = 0; ni < 2; ++ni)
        #pragma unroll
        for (int kk = 0; kk < 11; ++kk) {
          float v = feat[ni][kk];
          v += __shfl_xor(v, 16);
          v += __shfl_xor(v, 32);
          feat[ni][kk] = v;
        }

      if (quad == 0) {
        #pragma unroll
        for (int ni = 0; ni < 2; ++ni) {
          int q = ni * 16 + l15;
          if (q < 30) {
            #pragma unroll
            for (int kk = 0; kk < 11; ++kk) {
              int idx = q * 11 + kk;
              float prev = (c == 0) ? 0.0f : psum[ig][wv][idx];
              psum[ig][wv][idx] = prev + feat[ni][kk];
            }
          }
        }
      }
    }
  }
  __syncthreads();

  // block finish: sum 8 subwaves, log, qmask, dense-dot, one atomicAdd
  float s = 0.0f;
  if (t < 330) {
    int q = t / 11, kk = t % 11;
    float qm = qmask[b * 30 + q] * 0.01f;
    #pragma unroll
    for (int ig = 0; ig < 3; ++ig) {
      float v = 0.f;
      #pragma unroll
      for (int sub = 0; sub < 8; ++sub) v += psum[ig][sub][t];
      s += __logf(fmaxf(v, 1e-10f)) * qm * dw[(ig * 3 + tg) * 11 + kk];
    }
  }
  s += __shfl_xor(s, 1);  s += __shfl_xor(s, 2);  s += __shfl_xor(s, 4);
  s += __shfl_xor(s, 8);  s += __shfl_xor(s, 16); s += __shfl_xor(s, 32);
  if (lane == 0) wsum[wv] = s;
  __syncthreads();
  if (t == 0)
    atomicAdd(out + b, wsum[0] + wsum[1] + wsum[2] + wsum[3] +
                       wsum[4] + wsum[5] + wsum[6] + wsum[7]);
}

extern "C" void kernel_launch(void* const* d_in, const int* in_sizes, int n_in,
                              void* d_out, int out_size, void* d_ws, size_t ws_size,
                              hipStream_t stream) {
  const float* qemb  = (const float*)d_in[0];
  const float* demb  = (const float*)d_in[1];
  const float* qmask = (const float*)d_in[2];
  const float* dmask = (const float*)d_in[3];
  const float* w1 = (const float*)d_in[4];
  const float* b1 = (const float*)d_in[5];
  const float* w2 = (const float*)d_in[6];
  const float* b2 = (const float*)d_in[7];
  const float* w3 = (const float*)d_in[8];
  const float* b3 = (const float*)d_in[9];
  const float* dw = (const float*)d_in[10];

  unsigned short* ws  = (unsigned short*)d_ws;
  unsigned short* wt2 = ws;                       // 245760 shorts
  unsigned short* qn  = ws + 12042240;            // 1474560 shorts
  unsigned short* dn  = ws + 13516800;            // 12582912 shorts
  float* out = (float*)d_out;

  prep_w<<<960, 256, 0, stream>>>(w1, w2, w3, wt2);
  conv_all<<<1152, 512, 0, stream>>>(qemb, demb, wt2, b1, b2, b3, qn, dn);
  pool_final<<<384, 512, 0, stream>>>(qn, dn, qmask, dmask, dw, out);
}